// Round 2
// baseline (2415.020 us; speedup 1.0000x reference)
//
#include <hip/hip_runtime.h>
#include <math.h>

// Problem constants (from reference)
constexpr int B    = 512;
constexpr int NPG  = 200;    // nodes per graph, stage 0
constexpr int EPER = 2000;   // edges per graph
constexpr int EMB  = 9;
constexpr int HID  = 128;
constexpr int K1   = 160;    // ceil(0.8*200)
constexpr int K2   = 128;    // ceil(0.8*160)
constexpr int K3   = 103;    // ceil(0.8*128)
constexpr int N0   = B * NPG;   // 102400
constexpr int N1   = B * K1;    // 81920
constexpr int N2   = B * K2;    // 65536
constexpr int N3   = B * K3;    // 52736
constexpr int E    = B * EPER;  // 1024000

// ---------------------------------------------------------------------------
// Embedding gather: x0[n][:] = emb[node_ids[n]][:]
__global__ void k_gather(const int* __restrict__ node_ids,
                         const float* __restrict__ emb,
                         float* __restrict__ x0) {
    int n = blockIdx.x * blockDim.x + threadIdx.x;
    if (n < N0) {
        int id = node_ids[n];
        #pragma unroll
        for (int j = 0; j < EMB; j++) x0[n * EMB + j] = emb[id * EMB + j];
    }
}

// ---------------------------------------------------------------------------
// Stage-1 aggregation (width EMB=9), all edges valid. One block per graph,
// accumulate in LDS (per-graph node range is contiguous).
__global__ void k_agg9(const float* __restrict__ x0,
                       const int* __restrict__ esrc,
                       const int* __restrict__ edst,
                       float* __restrict__ s9,
                       float* __restrict__ cnt) {
    int g = blockIdx.x;
    __shared__ float lacc[NPG * EMB];
    __shared__ float lcnt[NPG];
    for (int i = threadIdx.x; i < NPG * EMB; i += 256) lacc[i] = 0.f;
    for (int i = threadIdx.x; i < NPG; i += 256) lcnt[i] = 0.f;
    __syncthreads();
    const int ebase = g * EPER;
    const int nbase = g * NPG;
    for (int idx = threadIdx.x; idx < EPER * EMB; idx += 256) {
        int el = idx / EMB;
        int j  = idx - el * EMB;
        int e  = ebase + el;
        int src = esrc[e];
        int dl  = edst[e] - nbase;
        atomicAdd(&lacc[dl * EMB + j], x0[src * EMB + j]);
        if (j == 0) atomicAdd(&lcnt[dl], 1.f);
    }
    __syncthreads();
    for (int i = threadIdx.x; i < NPG * EMB; i += 256) s9[nbase * EMB + i] = lacc[i];
    for (int i = threadIdx.x; i < NPG; i += 256) cnt[nbase + i] = lcnt[i];
}

// ---------------------------------------------------------------------------
// Stage-2/3 aggregation, CSR-based. One block per (graph, feature-half).
// Phase 1: build per-graph CSR in LDS (degrees -> scan -> scatter).
// Phase 2: dst-major accumulation in registers, one wave per dst, coalesced
// 256B row reads, no atomics in the hot loop. Degrees double as cnt.
__global__ void k_aggcsr(const float* __restrict__ x,
                         const int* __restrict__ esrc,
                         const int* __restrict__ edst,
                         const int* __restrict__ evalid,
                         int npc,
                         float* __restrict__ s,
                         float* __restrict__ cnt) {
    int g = blockIdx.x;
    int w = blockIdx.y;   // feature half (0/1)
    int tid = threadIdx.x;  // 256
    __shared__ int deg[256];
    __shared__ int scanbuf[256];
    __shared__ int off[257];
    __shared__ int cur[256];
    __shared__ int csr[EPER];

    deg[tid] = 0;
    __syncthreads();
    const int ebase = g * EPER;
    const int nbase = g * npc;
    // pass 1: degrees
    #pragma unroll 2
    for (int e = tid; e < EPER; e += 256) {
        int ee = ebase + e;
        if (evalid[ee]) atomicAdd(&deg[edst[ee] - nbase], 1);
    }
    __syncthreads();
    // Hillis-Steele inclusive scan over 256 entries
    int v = deg[tid];
    scanbuf[tid] = v;
    __syncthreads();
    #pragma unroll
    for (int d = 1; d < 256; d <<= 1) {
        int t = (tid >= d) ? scanbuf[tid - d] : 0;
        __syncthreads();
        scanbuf[tid] += t;
        __syncthreads();
    }
    if (tid == 0) off[0] = 0;
    off[tid + 1] = scanbuf[tid];
    __syncthreads();
    cur[tid] = off[tid];
    __syncthreads();
    // pass 2: scatter src ids into CSR slots
    #pragma unroll 2
    for (int e = tid; e < EPER; e += 256) {
        int ee = ebase + e;
        if (evalid[ee]) {
            int dl = edst[ee] - nbase;
            int slot = atomicAdd(&cur[dl], 1);
            csr[slot] = esrc[ee];
        }
    }
    __syncthreads();
    // phase 2: one wave per dst, register accumulation
    int lane = tid & 63, wv = tid >> 6;
    int hoff = w * 64 + lane;
    for (int dl = wv; dl < npc; dl += 4) {
        int beg = off[dl], end = off[dl + 1];
        float acc = 0.f, acc2 = 0.f;
        int t = beg;
        for (; t + 1 < end; t += 2) {
            acc  += x[(long)csr[t]     * HID + hoff];
            acc2 += x[(long)csr[t + 1] * HID + hoff];
        }
        if (t < end) acc += x[(long)csr[t] * HID + hoff];
        s[(long)(nbase + dl) * HID + hoff] = acc + acc2;
        if (w == 0 && lane == 0) cnt[nbase + dl] = (float)(end - beg);
    }
}

// ---------------------------------------------------------------------------
// Conv1: out[n][h] = relu( mean9[n] . w1n[h] + x0[n] . w1r[h] + b[h] )
template <int NB>
__global__ void k_conv1(const float* __restrict__ s9,
                        const float* __restrict__ cnt,
                        const float* __restrict__ x0,
                        const float* __restrict__ wn,
                        const float* __restrict__ wr,
                        const float* __restrict__ bb,
                        float* __restrict__ out) {
    __shared__ float sm[NB][EMB];
    __shared__ float sx[NB][EMB];
    int nb0 = blockIdx.x * NB;
    int h = threadIdx.x;  // 128
    for (int i = h; i < NB * EMB; i += 128) {
        int sl = i / EMB, j = i - sl * EMB;
        int n = nb0 + sl;
        float invc = 1.f / fmaxf(cnt[n], 1.f);
        sm[sl][j] = s9[n * EMB + j] * invc;
        sx[sl][j] = x0[n * EMB + j];
    }
    __syncthreads();
    float acc[NB];
    #pragma unroll
    for (int sl = 0; sl < NB; sl++) acc[sl] = bb[h];
    #pragma unroll
    for (int j = 0; j < EMB; j++) {
        float a = wn[h * EMB + j];
        float r = wr[h * EMB + j];
        #pragma unroll
        for (int sl = 0; sl < NB; sl++) acc[sl] += sm[sl][j] * a + sx[sl][j] * r;
    }
    #pragma unroll
    for (int sl = 0; sl < NB; sl++)
        out[(long)(nb0 + sl) * HID + h] = fmaxf(acc[sl], 0.f);
}

// ---------------------------------------------------------------------------
// Conv2/3: out[n][h] = relu( (s[n]/max(cnt,1)) . wn[h] + xin[n] . wr[h] + b[h] )
// May be called with out == s (in-place): all reads of s happen before the
// barrier, all writes after, and blocks touch disjoint node ranges.
template <int NB>
__global__ void k_conv128(const float* s,               // no restrict: may alias out
                          const float* __restrict__ cnt,
                          const float* __restrict__ xin,
                          const float* __restrict__ wn,
                          const float* __restrict__ wr,
                          const float* __restrict__ bb,
                          float* out) {
    __shared__ float sm[NB][HID];
    __shared__ float sx[NB][HID];
    int nb0 = blockIdx.x * NB;
    int h = threadIdx.x;  // 128
    for (int i = h; i < NB * HID; i += 128) {
        int sl = i >> 7, j = i & 127;
        int n = nb0 + sl;
        float invc = 1.f / fmaxf(cnt[n], 1.f);
        sm[sl][j] = s[(long)n * HID + j] * invc;
        sx[sl][j] = xin[(long)n * HID + j];
    }
    __syncthreads();
    float acc[NB];
    #pragma unroll
    for (int sl = 0; sl < NB; sl++) acc[sl] = bb[h];
    #pragma unroll 4
    for (int j = 0; j < HID; j++) {
        float a = wn[h * HID + j];
        float r = wr[h * HID + j];
        #pragma unroll
        for (int sl = 0; sl < NB; sl++) acc[sl] += sm[sl][j] * a + sx[sl][j] * r;
    }
    #pragma unroll
    for (int sl = 0; sl < NB; sl++)
        out[(long)(nb0 + sl) * HID + h] = fmaxf(acc[sl], 0.f);
}

// ---------------------------------------------------------------------------
// TopK pool: score = tanh(x.p/||p||); select top-k per graph with
// jax.lax.top_k semantics (descending, lower index wins ties); write
// xout[g*k+rank] = x[node]*score and mapping (old global id -> new or -1).
__global__ void k_pool(const float* __restrict__ x,
                       const float* __restrict__ p,
                       int npc, int k,
                       float* __restrict__ xout,
                       int* __restrict__ mapping) {
    int g = blockIdx.x;
    int tid = threadIdx.x;  // 256
    __shared__ float sc[256];
    __shared__ int   pos[256];
    __shared__ float red[256];
    // ||p||
    float v = 0.f;
    if (tid < HID) { float t = p[tid]; v = t * t; }
    red[tid] = v;
    __syncthreads();
    for (int off = 128; off >= 1; off >>= 1) {
        if (tid < off) red[tid] += red[tid + off];
        __syncthreads();
    }
    float nrm = sqrtf(red[0]);
    // scores
    float scv = 0.f;
    if (tid < npc) {
        const float* xr = x + (long)(g * npc + tid) * HID;
        float d = 0.f;
        #pragma unroll 4
        for (int j = 0; j < HID; j++) d += xr[j] * p[j];
        scv = tanhf(d / nrm);
        sc[tid] = scv;
    }
    __syncthreads();
    // rank = position in descending stable order
    if (tid < npc) {
        int rank = 0;
        for (int j = 0; j < npc; j++) {
            float o = sc[j];
            rank += (o > scv) || (o == scv && j < tid);
        }
        bool keep = rank < k;
        pos[tid] = keep ? rank : -1;
        mapping[g * npc + tid] = keep ? (g * k + rank) : -1;
    }
    __syncthreads();
    // gather + scale into new ordering
    for (int idx = tid; idx < npc * HID; idx += 256) {
        int i = idx >> 7, h = idx & 127;
        int r = pos[i];
        if (r >= 0)
            xout[(long)(g * k + r) * HID + h] = x[(long)(g * npc + i) * HID + h] * sc[i];
    }
}

// ---------------------------------------------------------------------------
// Edge remap after pooling. May run in-place (sin==sout etc): each thread
// reads then writes only its own slot.
__global__ void k_edgeupd(const int* sin, const int* din, const int* vin,
                          const int* __restrict__ mapping,
                          int* sout, int* dout, int* vout) {
    int e = blockIdx.x * blockDim.x + threadIdx.x;
    if (e < E) {
        int v  = vin ? vin[e] : 1;
        int ns = mapping[sin[e]];
        int nd = mapping[din[e]];
        int nv = (v && ns >= 0 && nd >= 0) ? 1 : 0;
        sout[e] = ns >= 0 ? ns : 0;
        dout[e] = nd >= 0 ? nd : 0;
        vout[e] = nv;
    }
}

// ---------------------------------------------------------------------------
// Global pool: gout[g][0:128]=max over k rows, gout[g][128:256]=mean.
__global__ void k_gpool(const float* __restrict__ x, int k,
                        float* __restrict__ gout) {
    int g = blockIdx.x, h = threadIdx.x;  // 128 threads
    float mx = -INFINITY, sm = 0.f;
    for (int i = 0; i < k; i++) {
        float v = x[(long)(g * k + i) * HID + h];
        mx = fmaxf(mx, v);
        sm += v;
    }
    gout[g * 256 + h] = mx;
    gout[g * 256 + 128 + h] = sm / (float)k;
}

// ---------------------------------------------------------------------------
// MLP head: h=g1+g2+g3; relu(h@lw1.T+lb1); relu(@lw2.T+lb2); sigmoid(@lw3.T+lb3)
__global__ void k_mlp(const float* __restrict__ g1, const float* __restrict__ g2,
                      const float* __restrict__ g3,
                      const float* __restrict__ lw1, const float* __restrict__ lb1,
                      const float* __restrict__ lw2, const float* __restrict__ lb2,
                      const float* __restrict__ lw3, const float* __restrict__ lb3,
                      float* __restrict__ out) {
    int g = blockIdx.x, t = threadIdx.x;  // 128 threads
    __shared__ float h0[256];
    __shared__ float h1[128];
    __shared__ float h2r[64];
    h0[t]       = g1[g * 256 + t] + g2[g * 256 + t] + g3[g * 256 + t];
    h0[t + 128] = g1[g * 256 + 128 + t] + g2[g * 256 + 128 + t] + g3[g * 256 + 128 + t];
    __syncthreads();
    float a = lb1[t];
    #pragma unroll 4
    for (int j = 0; j < 256; j++) a += h0[j] * lw1[t * 256 + j];
    h1[t] = fmaxf(a, 0.f);
    __syncthreads();
    if (t < 64) {
        float a2 = lb2[t];
        #pragma unroll 4
        for (int j = 0; j < 128; j++) a2 += h1[j] * lw2[t * 128 + j];
        h2r[t] = fmaxf(a2, 0.f) * lw3[t];
    }
    __syncthreads();
    if (t == 0) {
        float s = 0.f;
        for (int j = 0; j < 64; j++) s += h2r[j];
        s += lb3[0];
        out[g] = 1.f / (1.f + expf(-s));
    }
}

// ---------------------------------------------------------------------------
extern "C" void kernel_launch(void* const* d_in, const int* in_sizes, int n_in,
                              void* d_out, int out_size, void* d_ws, size_t ws_size,
                              hipStream_t stream) {
    const int*   node_ids = (const int*)d_in[0];
    const int*   ei   = (const int*)d_in[1];   // edge_index (2, E)
    const float* emb  = (const float*)d_in[3];
    const float* w1n  = (const float*)d_in[4];
    const float* w1r  = (const float*)d_in[5];
    const float* b1   = (const float*)d_in[6];
    const float* w2n  = (const float*)d_in[7];
    const float* w2r  = (const float*)d_in[8];
    const float* b2   = (const float*)d_in[9];
    const float* w3n  = (const float*)d_in[10];
    const float* w3r  = (const float*)d_in[11];
    const float* b3   = (const float*)d_in[12];
    const float* p1   = (const float*)d_in[13];
    const float* p2   = (const float*)d_in[14];
    const float* p3   = (const float*)d_in[15];
    const float* lw1  = (const float*)d_in[16];
    const float* lb1  = (const float*)d_in[17];
    const float* lw2  = (const float*)d_in[18];
    const float* lb2  = (const float*)d_in[19];
    const float* lw3  = (const float*)d_in[20];
    const float* lb3  = (const float*)d_in[21];
    float* out = (float*)d_out;

    // Workspace layout (floats). x0/s9 alias the front of D (dead before
    // D's first real use as pool-1 output).
    float* ws  = (float*)d_ws;
    float* C   = ws;                           // N0*HID   (x1 / s-acc / x2 / s3 / x3)
    float* D   = C + (size_t)N0 * HID;         // N1*HID   (x1p / x2p / x3p)
    float* x0  = D;                            // N0*EMB   (stage 1 only)
    float* s9  = D + (size_t)N0 * EMB;         // N0*EMB   (stage 1 only)
    float* cnt = D + (size_t)N1 * HID;         // N0
    float* g1  = cnt + N0;                     // B*256
    float* g2  = g1 + B * 2 * HID;             // B*256
    float* g3  = g2 + B * 2 * HID;             // B*256
    int* mapping = (int*)(g3 + B * 2 * HID);   // N0
    int* esrc  = mapping + N0;                 // E
    int* edst  = esrc + E;                     // E
    int* evalid = edst + E;                    // E

    // ---- Stage 1 (EMB -> HID) ----
    k_gather<<<(N0 + 255) / 256, 256, 0, stream>>>(node_ids, emb, x0);
    k_agg9<<<B, 256, 0, stream>>>(x0, ei, ei + E, s9, cnt);
    k_conv1<8><<<N0 / 8, 128, 0, stream>>>(s9, cnt, x0, w1n, w1r, b1, C);
    k_pool<<<B, 256, 0, stream>>>(C, p1, NPG, K1, D, mapping);
    k_edgeupd<<<(E + 255) / 256, 256, 0, stream>>>(ei, ei + E, nullptr, mapping,
                                                   esrc, edst, evalid);
    k_gpool<<<B, 128, 0, stream>>>(D, K1, g1);

    // ---- Stage 2 (HID -> HID), nodes N1 ----
    k_aggcsr<<<dim3(B, 2), 256, 0, stream>>>(D, esrc, edst, evalid, K1, C, cnt);
    k_conv128<16><<<N1 / 16, 128, 0, stream>>>(C, cnt, D, w2n, w2r, b2, C);
    k_pool<<<B, 256, 0, stream>>>(C, p2, K1, K2, D, mapping);
    k_edgeupd<<<(E + 255) / 256, 256, 0, stream>>>(esrc, edst, evalid, mapping,
                                                   esrc, edst, evalid);
    k_gpool<<<B, 128, 0, stream>>>(D, K2, g2);

    // ---- Stage 3 (HID -> HID), nodes N2 ----
    k_aggcsr<<<dim3(B, 2), 256, 0, stream>>>(D, esrc, edst, evalid, K2, C, cnt);
    k_conv128<16><<<N2 / 16, 128, 0, stream>>>(C, cnt, D, w3n, w3r, b3, C);
    k_pool<<<B, 256, 0, stream>>>(C, p3, K2, K3, D, mapping);
    // (final edge update is unused by the reference output -> skipped)
    k_gpool<<<B, 128, 0, stream>>>(D, K3, g3);

    // ---- Head ----
    k_mlp<<<B, 128, 0, stream>>>(g1, g2, g3, lw1, lb1, lw2, lb2, lw3, lb3, out);
}

// Round 3
// 1283.201 us; speedup vs baseline: 1.8820x; 1.8820x over previous
//
#include <hip/hip_runtime.h>
#include <math.h>

// Problem constants (from reference)
constexpr int B    = 512;
constexpr int NPG  = 200;    // nodes per graph, stage 0
constexpr int EPER = 2000;   // edges per graph
constexpr int EMB  = 9;
constexpr int HID  = 128;
constexpr int K1   = 160;    // ceil(0.8*200)
constexpr int K2   = 128;    // ceil(0.8*160)
constexpr int K3   = 103;    // ceil(0.8*128)
constexpr int N0   = B * NPG;   // 102400
constexpr int N1   = B * K1;    // 81920
constexpr int N2   = B * K2;    // 65536
constexpr int N3   = B * K3;    // 52736
constexpr int E    = B * EPER;  // 1024000

// ---------------------------------------------------------------------------
// Embedding gather: x0[n][:] = emb[node_ids[n]][:]
__global__ __launch_bounds__(256) void k_gather(const int* __restrict__ node_ids,
                         const float* __restrict__ emb,
                         float* __restrict__ x0) {
    int n = blockIdx.x * blockDim.x + threadIdx.x;
    if (n < N0) {
        int id = node_ids[n];
        #pragma unroll
        for (int j = 0; j < EMB; j++) x0[n * EMB + j] = emb[id * EMB + j];
    }
}

// ---------------------------------------------------------------------------
// Stage-1 aggregation (width EMB=9), all edges valid. One block per graph,
// accumulate in LDS (per-graph node range is contiguous).
__global__ __launch_bounds__(256) void k_agg9(const float* __restrict__ x0,
                       const int* __restrict__ esrc,
                       const int* __restrict__ edst,
                       float* __restrict__ s9,
                       float* __restrict__ cnt) {
    int g = blockIdx.x;
    __shared__ float lacc[NPG * EMB];
    __shared__ float lcnt[NPG];
    for (int i = threadIdx.x; i < NPG * EMB; i += 256) lacc[i] = 0.f;
    for (int i = threadIdx.x; i < NPG; i += 256) lcnt[i] = 0.f;
    __syncthreads();
    const int ebase = g * EPER;
    const int nbase = g * NPG;
    for (int idx = threadIdx.x; idx < EPER * EMB; idx += 256) {
        int el = idx / EMB;
        int j  = idx - el * EMB;
        int e  = ebase + el;
        int src = esrc[e];
        int dl  = edst[e] - nbase;
        atomicAdd(&lacc[dl * EMB + j], x0[src * EMB + j]);
        if (j == 0) atomicAdd(&lcnt[dl], 1.f);
    }
    __syncthreads();
    for (int i = threadIdx.x; i < NPG * EMB; i += 256) s9[nbase * EMB + i] = lacc[i];
    for (int i = threadIdx.x; i < NPG; i += 256) cnt[nbase + i] = lcnt[i];
}

// ---------------------------------------------------------------------------
// Stage-2/3 aggregation, CSR-based. One block per (graph, feature-half).
__global__ __launch_bounds__(256) void k_aggcsr(const float* __restrict__ x,
                         const int* __restrict__ esrc,
                         const int* __restrict__ edst,
                         const int* __restrict__ evalid,
                         int npc,
                         float* __restrict__ s,
                         float* __restrict__ cnt) {
    int g = blockIdx.x;
    int w = blockIdx.y;   // feature half (0/1)
    int tid = threadIdx.x;  // 256
    __shared__ int deg[256];
    __shared__ int scanbuf[256];
    __shared__ int off[257];
    __shared__ int cur[256];
    __shared__ int csr[EPER];

    deg[tid] = 0;
    __syncthreads();
    const int ebase = g * EPER;
    const int nbase = g * npc;
    // pass 1: degrees
    #pragma unroll 2
    for (int e = tid; e < EPER; e += 256) {
        int ee = ebase + e;
        if (evalid[ee]) atomicAdd(&deg[edst[ee] - nbase], 1);
    }
    __syncthreads();
    // Hillis-Steele inclusive scan over 256 entries
    int v = deg[tid];
    scanbuf[tid] = v;
    __syncthreads();
    #pragma unroll
    for (int d = 1; d < 256; d <<= 1) {
        int t = (tid >= d) ? scanbuf[tid - d] : 0;
        __syncthreads();
        scanbuf[tid] += t;
        __syncthreads();
    }
    if (tid == 0) off[0] = 0;
    off[tid + 1] = scanbuf[tid];
    __syncthreads();
    cur[tid] = off[tid];
    __syncthreads();
    // pass 2: scatter src ids into CSR slots
    #pragma unroll 2
    for (int e = tid; e < EPER; e += 256) {
        int ee = ebase + e;
        if (evalid[ee]) {
            int dl = edst[ee] - nbase;
            int slot = atomicAdd(&cur[dl], 1);
            csr[slot] = esrc[ee];
        }
    }
    __syncthreads();
    // phase 2: one wave per dst, register accumulation
    int lane = tid & 63, wv = tid >> 6;
    int hoff = w * 64 + lane;
    for (int dl = wv; dl < npc; dl += 4) {
        int beg = off[dl], end = off[dl + 1];
        float acc = 0.f, acc2 = 0.f;
        int t = beg;
        for (; t + 1 < end; t += 2) {
            acc  += x[(long)csr[t]     * HID + hoff];
            acc2 += x[(long)csr[t + 1] * HID + hoff];
        }
        if (t < end) acc += x[(long)csr[t] * HID + hoff];
        s[(long)(nbase + dl) * HID + hoff] = acc + acc2;
        if (w == 0 && lane == 0) cnt[nbase + dl] = (float)(end - beg);
    }
}

// ---------------------------------------------------------------------------
// Conv1: out[n][h] = relu( mean9[n] . w1n[h] + x0[n] . w1r[h] + b[h] )
template <int NB>
__global__ __launch_bounds__(128) void k_conv1(const float* __restrict__ s9,
                        const float* __restrict__ cnt,
                        const float* __restrict__ x0,
                        const float* __restrict__ wn,
                        const float* __restrict__ wr,
                        const float* __restrict__ bb,
                        float* __restrict__ out) {
    __shared__ float sm[NB][EMB];
    __shared__ float sx[NB][EMB];
    int nb0 = blockIdx.x * NB;
    int h = threadIdx.x;  // 128
    for (int i = h; i < NB * EMB; i += 128) {
        int sl = i / EMB, j = i - sl * EMB;
        int n = nb0 + sl;
        float invc = 1.f / fmaxf(cnt[n], 1.f);
        sm[sl][j] = s9[n * EMB + j] * invc;
        sx[sl][j] = x0[n * EMB + j];
    }
    __syncthreads();
    float acc[NB];
    #pragma unroll
    for (int sl = 0; sl < NB; sl++) acc[sl] = bb[h];
    #pragma unroll
    for (int j = 0; j < EMB; j++) {
        float a = wn[h * EMB + j];
        float r = wr[h * EMB + j];
        #pragma unroll
        for (int sl = 0; sl < NB; sl++) acc[sl] += sm[sl][j] * a + sx[sl][j] * r;
    }
    #pragma unroll
    for (int sl = 0; sl < NB; sl++)
        out[(long)(nb0 + sl) * HID + h] = fmaxf(acc[sl], 0.f);
}

// ---------------------------------------------------------------------------
// Conv2/3 register-GEMM: each thread holds one full 128-float weight row in
// VGPRs (32 float4). 256 threads: waves 0-1 (rep=0) compute dotS with wn,
// waves 2-3 (rep=1) compute dotX with wr. Node-row loads are wave-uniform
// (address independent of lane) -> scalarizable / single-L1-line.
// out[n][h] = relu(dotS*invc[n] + dotX + b[h]). May run in-place (out==s):
// all s reads complete before the barrier, stores after; blocks own disjoint
// rows.
template <int NT>
__global__ __launch_bounds__(256, 2) void k_convreg(
        const float* s,                      // may alias out
        const float* __restrict__ cnt,
        const float* __restrict__ xin,
        const float* __restrict__ wn,
        const float* __restrict__ wr,
        const float* __restrict__ bb,
        float* out) {
    int t = threadIdx.x;
    int h = t & 127;
    int rep = t >> 7;
    long nb0 = (long)blockIdx.x * NT;

    const float* wsrc = rep ? wr : wn;
    const float4* wrow = (const float4*)(wsrc + (size_t)h * HID);
    float4 w[32];
    #pragma unroll
    for (int j = 0; j < 32; j++) w[j] = wrow[j];

    const float* xsrc = rep ? xin : s;
    float acc[NT];
    #pragma unroll
    for (int n = 0; n < NT; n++) {
        const float4* xr = (const float4*)(xsrc + (nb0 + n) * HID);
        float a = 0.f;
        #pragma unroll
        for (int j = 0; j < 32; j++) {
            float4 xv = xr[j];
            a += xv.x * w[j].x + xv.y * w[j].y + xv.z * w[j].z + xv.w * w[j].w;
        }
        acc[n] = a;
    }

    __shared__ float ldsX[NT][HID];
    if (rep == 1) {
        #pragma unroll
        for (int n = 0; n < NT; n++) ldsX[n][h] = acc[n];
    }
    __syncthreads();
    if (rep == 0) {
        #pragma unroll
        for (int n = 0; n < NT; n++) {
            float invc = 1.f / fmaxf(cnt[nb0 + n], 1.f);
            out[(nb0 + n) * HID + h] =
                fmaxf(acc[n] * invc + ldsX[n][h] + bb[h], 0.f);
        }
    }
}

// ---------------------------------------------------------------------------
// TopK pool: score = tanh(x.p/||p||); select top-k per graph with
// jax.lax.top_k semantics (descending, lower index wins ties); write
// xout[g*k+rank] = x[node]*score and mapping (old global id -> new or -1).
__global__ __launch_bounds__(256) void k_pool(const float* __restrict__ x,
                       const float* __restrict__ p,
                       int npc, int k,
                       float* __restrict__ xout,
                       int* __restrict__ mapping) {
    int g = blockIdx.x;
    int tid = threadIdx.x;  // 256
    __shared__ float sc[256];
    __shared__ int   pos[256];
    __shared__ float red[256];
    // ||p||
    float v = 0.f;
    if (tid < HID) { float t = p[tid]; v = t * t; }
    red[tid] = v;
    __syncthreads();
    for (int off = 128; off >= 1; off >>= 1) {
        if (tid < off) red[tid] += red[tid + off];
        __syncthreads();
    }
    float nrm = sqrtf(red[0]);
    // scores
    float scv = 0.f;
    if (tid < npc) {
        const float* xr = x + (long)(g * npc + tid) * HID;
        float d = 0.f;
        #pragma unroll 4
        for (int j = 0; j < HID; j++) d += xr[j] * p[j];
        scv = tanhf(d / nrm);
        sc[tid] = scv;
    }
    __syncthreads();
    // rank = position in descending stable order
    if (tid < npc) {
        int rank = 0;
        for (int j = 0; j < npc; j++) {
            float o = sc[j];
            rank += (o > scv) || (o == scv && j < tid);
        }
        bool keep = rank < k;
        pos[tid] = keep ? rank : -1;
        mapping[g * npc + tid] = keep ? (g * k + rank) : -1;
    }
    __syncthreads();
    // gather + scale into new ordering
    for (int idx = tid; idx < npc * HID; idx += 256) {
        int i = idx >> 7, h = idx & 127;
        int r = pos[i];
        if (r >= 0)
            xout[(long)(g * k + r) * HID + h] = x[(long)(g * npc + i) * HID + h] * sc[i];
    }
}

// ---------------------------------------------------------------------------
// Edge remap after pooling. May run in-place (sin==sout etc): each thread
// reads then writes only its own slot.
__global__ __launch_bounds__(256) void k_edgeupd(const int* sin, const int* din, const int* vin,
                          const int* __restrict__ mapping,
                          int* sout, int* dout, int* vout) {
    int e = blockIdx.x * blockDim.x + threadIdx.x;
    if (e < E) {
        int v  = vin ? vin[e] : 1;
        int ns = mapping[sin[e]];
        int nd = mapping[din[e]];
        int nv = (v && ns >= 0 && nd >= 0) ? 1 : 0;
        sout[e] = ns >= 0 ? ns : 0;
        dout[e] = nd >= 0 ? nd : 0;
        vout[e] = nv;
    }
}

// ---------------------------------------------------------------------------
// Global pool: gout[g][0:128]=max over k rows, gout[g][128:256]=mean.
__global__ __launch_bounds__(128) void k_gpool(const float* __restrict__ x, int k,
                        float* __restrict__ gout) {
    int g = blockIdx.x, h = threadIdx.x;  // 128 threads
    float mx = -INFINITY, sm = 0.f;
    for (int i = 0; i < k; i++) {
        float v = x[(long)(g * k + i) * HID + h];
        mx = fmaxf(mx, v);
        sm += v;
    }
    gout[g * 256 + h] = mx;
    gout[g * 256 + 128 + h] = sm / (float)k;
}

// ---------------------------------------------------------------------------
// MLP head: h=g1+g2+g3; relu(h@lw1.T+lb1); relu(@lw2.T+lb2); sigmoid(@lw3.T+lb3)
__global__ __launch_bounds__(128) void k_mlp(const float* __restrict__ g1, const float* __restrict__ g2,
                      const float* __restrict__ g3,
                      const float* __restrict__ lw1, const float* __restrict__ lb1,
                      const float* __restrict__ lw2, const float* __restrict__ lb2,
                      const float* __restrict__ lw3, const float* __restrict__ lb3,
                      float* __restrict__ out) {
    int g = blockIdx.x, t = threadIdx.x;  // 128 threads
    __shared__ float h0[256];
    __shared__ float h1[128];
    __shared__ float h2r[64];
    h0[t]       = g1[g * 256 + t] + g2[g * 256 + t] + g3[g * 256 + t];
    h0[t + 128] = g1[g * 256 + 128 + t] + g2[g * 256 + 128 + t] + g3[g * 256 + 128 + t];
    __syncthreads();
    float a = lb1[t];
    #pragma unroll 4
    for (int j = 0; j < 256; j++) a += h0[j] * lw1[t * 256 + j];
    h1[t] = fmaxf(a, 0.f);
    __syncthreads();
    if (t < 64) {
        float a2 = lb2[t];
        #pragma unroll 4
        for (int j = 0; j < 128; j++) a2 += h1[j] * lw2[t * 128 + j];
        h2r[t] = fmaxf(a2, 0.f) * lw3[t];
    }
    __syncthreads();
    if (t == 0) {
        float s = 0.f;
        for (int j = 0; j < 64; j++) s += h2r[j];
        s += lb3[0];
        out[g] = 1.f / (1.f + expf(-s));
    }
}

// ---------------------------------------------------------------------------
extern "C" void kernel_launch(void* const* d_in, const int* in_sizes, int n_in,
                              void* d_out, int out_size, void* d_ws, size_t ws_size,
                              hipStream_t stream) {
    const int*   node_ids = (const int*)d_in[0];
    const int*   ei   = (const int*)d_in[1];   // edge_index (2, E)
    const float* emb  = (const float*)d_in[3];
    const float* w1n  = (const float*)d_in[4];
    const float* w1r  = (const float*)d_in[5];
    const float* b1   = (const float*)d_in[6];
    const float* w2n  = (const float*)d_in[7];
    const float* w2r  = (const float*)d_in[8];
    const float* b2   = (const float*)d_in[9];
    const float* w3n  = (const float*)d_in[10];
    const float* w3r  = (const float*)d_in[11];
    const float* b3   = (const float*)d_in[12];
    const float* p1   = (const float*)d_in[13];
    const float* p2   = (const float*)d_in[14];
    const float* p3   = (const float*)d_in[15];
    const float* lw1  = (const float*)d_in[16];
    const float* lb1  = (const float*)d_in[17];
    const float* lw2  = (const float*)d_in[18];
    const float* lb2  = (const float*)d_in[19];
    const float* lw3  = (const float*)d_in[20];
    const float* lb3  = (const float*)d_in[21];
    float* out = (float*)d_out;

    // Workspace layout (floats). x0/s9 alias the front of D (dead before
    // D's first real use as pool-1 output).
    float* ws  = (float*)d_ws;
    float* C   = ws;                           // N0*HID   (x1 / s-acc / x2 / s3 / x3)
    float* D   = C + (size_t)N0 * HID;         // N1*HID   (x1p / x2p / x3p)
    float* x0  = D;                            // N0*EMB   (stage 1 only)
    float* s9  = D + (size_t)N0 * EMB;         // N0*EMB   (stage 1 only)
    float* cnt = D + (size_t)N1 * HID;         // N0
    float* g1  = cnt + N0;                     // B*256
    float* g2  = g1 + B * 2 * HID;             // B*256
    float* g3  = g2 + B * 2 * HID;             // B*256
    int* mapping = (int*)(g3 + B * 2 * HID);   // N0
    int* esrc  = mapping + N0;                 // E
    int* edst  = esrc + E;                     // E
    int* evalid = edst + E;                    // E

    // ---- Stage 1 (EMB -> HID) ----
    k_gather<<<(N0 + 255) / 256, 256, 0, stream>>>(node_ids, emb, x0);
    k_agg9<<<B, 256, 0, stream>>>(x0, ei, ei + E, s9, cnt);
    k_conv1<8><<<N0 / 8, 128, 0, stream>>>(s9, cnt, x0, w1n, w1r, b1, C);
    k_pool<<<B, 256, 0, stream>>>(C, p1, NPG, K1, D, mapping);
    k_edgeupd<<<(E + 255) / 256, 256, 0, stream>>>(ei, ei + E, nullptr, mapping,
                                                   esrc, edst, evalid);
    k_gpool<<<B, 128, 0, stream>>>(D, K1, g1);

    // ---- Stage 2 (HID -> HID), nodes N1 ----
    k_aggcsr<<<dim3(B, 2), 256, 0, stream>>>(D, esrc, edst, evalid, K1, C, cnt);
    k_convreg<16><<<N1 / 16, 256, 0, stream>>>(C, cnt, D, w2n, w2r, b2, C);
    k_pool<<<B, 256, 0, stream>>>(C, p2, K1, K2, D, mapping);
    k_edgeupd<<<(E + 255) / 256, 256, 0, stream>>>(esrc, edst, evalid, mapping,
                                                   esrc, edst, evalid);
    k_gpool<<<B, 128, 0, stream>>>(D, K2, g2);

    // ---- Stage 3 (HID -> HID), nodes N2 ----
    k_aggcsr<<<dim3(B, 2), 256, 0, stream>>>(D, esrc, edst, evalid, K2, C, cnt);
    k_convreg<16><<<N2 / 16, 256, 0, stream>>>(C, cnt, D, w3n, w3r, b3, C);
    k_pool<<<B, 256, 0, stream>>>(C, p3, K2, K3, D, mapping);
    // (final edge update is unused by the reference output -> skipped)
    k_gpool<<<B, 128, 0, stream>>>(D, K3, g3);

    // ---- Head ----
    k_mlp<<<B, 128, 0, stream>>>(g1, g2, g3, lw1, lb1, lw2, lb2, lw3, lb3, out);
}

// Round 4
// 716.996 us; speedup vs baseline: 3.3682x; 1.7897x over previous
//
#include <hip/hip_runtime.h>
#include <math.h>

// Problem constants (from reference)
constexpr int B    = 512;
constexpr int NPG  = 200;    // nodes per graph, stage 0
constexpr int EPER = 2000;   // edges per graph
constexpr int EMB  = 9;
constexpr int HID  = 128;
constexpr int K1   = 160;    // ceil(0.8*200)
constexpr int K2   = 128;    // ceil(0.8*160)
constexpr int K3   = 103;    // ceil(0.8*128)
constexpr int N0   = B * NPG;   // 102400
constexpr int N1   = B * K1;    // 81920
constexpr int N2   = B * K2;    // 65536
constexpr int N3   = B * K3;    // 52736
constexpr int E    = B * EPER;  // 1024000

// ---------------------------------------------------------------------------
// Embedding gather: x0[n][:] = emb[node_ids[n]][:]
__global__ __launch_bounds__(256) void k_gather(const int* __restrict__ node_ids,
                         const float* __restrict__ emb,
                         float* __restrict__ x0) {
    int n = blockIdx.x * blockDim.x + threadIdx.x;
    if (n < N0) {
        int id = node_ids[n];
        #pragma unroll
        for (int j = 0; j < EMB; j++) x0[n * EMB + j] = emb[id * EMB + j];
    }
}

// ---------------------------------------------------------------------------
// Stage-1 aggregation (width EMB=9), all edges valid. One block per graph,
// accumulate in LDS (per-graph node range is contiguous).
__global__ __launch_bounds__(256) void k_agg9(const float* __restrict__ x0,
                       const int* __restrict__ esrc,
                       const int* __restrict__ edst,
                       float* __restrict__ s9,
                       float* __restrict__ cnt) {
    int g = blockIdx.x;
    __shared__ float lacc[NPG * EMB];
    __shared__ float lcnt[NPG];
    for (int i = threadIdx.x; i < NPG * EMB; i += 256) lacc[i] = 0.f;
    for (int i = threadIdx.x; i < NPG; i += 256) lcnt[i] = 0.f;
    __syncthreads();
    const int ebase = g * EPER;
    const int nbase = g * NPG;
    for (int idx = threadIdx.x; idx < EPER * EMB; idx += 256) {
        int el = idx / EMB;
        int j  = idx - el * EMB;
        int e  = ebase + el;
        int src = esrc[e];
        int dl  = edst[e] - nbase;
        atomicAdd(&lacc[dl * EMB + j], x0[src * EMB + j]);
        if (j == 0) atomicAdd(&lcnt[dl], 1.f);
    }
    __syncthreads();
    for (int i = threadIdx.x; i < NPG * EMB; i += 256) s9[nbase * EMB + i] = lacc[i];
    for (int i = threadIdx.x; i < NPG; i += 256) cnt[nbase + i] = lcnt[i];
}

// ---------------------------------------------------------------------------
// Stage-2/3 aggregation, CSR-based. One block per (graph, feature-half).
__global__ __launch_bounds__(256) void k_aggcsr(const float* __restrict__ x,
                         const int* __restrict__ esrc,
                         const int* __restrict__ edst,
                         const int* __restrict__ evalid,
                         int npc,
                         float* __restrict__ s,
                         float* __restrict__ cnt) {
    int g = blockIdx.x;
    int w = blockIdx.y;   // feature half (0/1)
    int tid = threadIdx.x;  // 256
    __shared__ int deg[256];
    __shared__ int scanbuf[256];
    __shared__ int off[257];
    __shared__ int cur[256];
    __shared__ int csr[EPER];

    deg[tid] = 0;
    __syncthreads();
    const int ebase = g * EPER;
    const int nbase = g * npc;
    // pass 1: degrees
    #pragma unroll 2
    for (int e = tid; e < EPER; e += 256) {
        int ee = ebase + e;
        if (evalid[ee]) atomicAdd(&deg[edst[ee] - nbase], 1);
    }
    __syncthreads();
    // Hillis-Steele inclusive scan over 256 entries
    int v = deg[tid];
    scanbuf[tid] = v;
    __syncthreads();
    #pragma unroll
    for (int d = 1; d < 256; d <<= 1) {
        int t = (tid >= d) ? scanbuf[tid - d] : 0;
        __syncthreads();
        scanbuf[tid] += t;
        __syncthreads();
    }
    if (tid == 0) off[0] = 0;
    off[tid + 1] = scanbuf[tid];
    __syncthreads();
    cur[tid] = off[tid];
    __syncthreads();
    // pass 2: scatter src ids into CSR slots
    #pragma unroll 2
    for (int e = tid; e < EPER; e += 256) {
        int ee = ebase + e;
        if (evalid[ee]) {
            int dl = edst[ee] - nbase;
            int slot = atomicAdd(&cur[dl], 1);
            csr[slot] = esrc[ee];
        }
    }
    __syncthreads();
    // phase 2: one wave per dst, register accumulation
    int lane = tid & 63, wv = tid >> 6;
    int hoff = w * 64 + lane;
    for (int dl = wv; dl < npc; dl += 4) {
        int beg = off[dl], end = off[dl + 1];
        float acc = 0.f, acc2 = 0.f;
        int t = beg;
        for (; t + 1 < end; t += 2) {
            acc  += x[(long)csr[t]     * HID + hoff];
            acc2 += x[(long)csr[t + 1] * HID + hoff];
        }
        if (t < end) acc += x[(long)csr[t] * HID + hoff];
        s[(long)(nbase + dl) * HID + hoff] = acc + acc2;
        if (w == 0 && lane == 0) cnt[nbase + dl] = (float)(end - beg);
    }
}

// ---------------------------------------------------------------------------
// Conv1: out[n][h] = relu( mean9[n] . w1n[h] + x0[n] . w1r[h] + b[h] )
template <int NB>
__global__ __launch_bounds__(128) void k_conv1(const float* __restrict__ s9,
                        const float* __restrict__ cnt,
                        const float* __restrict__ x0,
                        const float* __restrict__ wn,
                        const float* __restrict__ wr,
                        const float* __restrict__ bb,
                        float* __restrict__ out) {
    __shared__ float sm[NB][EMB];
    __shared__ float sx[NB][EMB];
    int nb0 = blockIdx.x * NB;
    int h = threadIdx.x;  // 128
    for (int i = h; i < NB * EMB; i += 128) {
        int sl = i / EMB, j = i - sl * EMB;
        int n = nb0 + sl;
        float invc = 1.f / fmaxf(cnt[n], 1.f);
        sm[sl][j] = s9[n * EMB + j] * invc;
        sx[sl][j] = x0[n * EMB + j];
    }
    __syncthreads();
    float acc[NB];
    #pragma unroll
    for (int sl = 0; sl < NB; sl++) acc[sl] = bb[h];
    #pragma unroll
    for (int j = 0; j < EMB; j++) {
        float a = wn[h * EMB + j];
        float r = wr[h * EMB + j];
        #pragma unroll
        for (int sl = 0; sl < NB; sl++) acc[sl] += sm[sl][j] * a + sx[sl][j] * r;
    }
    #pragma unroll
    for (int sl = 0; sl < NB; sl++)
        out[(long)(nb0 + sl) * HID + h] = fmaxf(acc[sl], 0.f);
}

// ---------------------------------------------------------------------------
// Conv2/3 as LDS-tiled fp32 GEMM with K=256 (concat [s*invc, x] against
// [wn; wr] rows). Block = 128 rows x 128 cols, 256 threads, 8x8 register
// tile per thread. K streamed in 8 chunks of 32, k-major (transposed) LDS
// tiles. Thread (tr=tid/16, tc=tid%16): rows tr*8..+8, cols {4tc..4tc+3,
// 64+4tc..+3} (column split keeps B-reads at 2-way bank alias = free).
// A-reads broadcast across 16 lanes (free). Global loads for chunk c+1
// prefetched into registers during compute of chunk c.
// In-place safe (out may alias s): block reads only its own 128 rows of s,
// all during staging, which completes before the epilogue stores.
constexpr int GP = 132;  // LDS row pitch (floats): 16B-aligned, breaks pow-2
__global__ __launch_bounds__(256, 2) void k_convgemm(
        const float* s,                      // may alias out
        const float* __restrict__ cnt,
        const float* xin,
        const float* __restrict__ wn,
        const float* __restrict__ wr,
        const float* __restrict__ bb,
        float* out) {
    __shared__ float As[32 * GP];
    __shared__ float Bs[32 * GP];
    __shared__ float invc_s[128];
    const int tid = threadIdx.x;
    const long row0 = (long)blockIdx.x * 128;
    if (tid < 128) invc_s[tid] = 1.f / fmaxf(cnt[row0 + tid], 1.f);

    const int tc = tid & 15, tr = tid >> 4;
    const int srow = tid >> 3;        // 0..31 (+i*32)
    const int scol = (tid & 7) * 4;   // k-offset within chunk: 0,4,..,28

    float acc[8][8];
    #pragma unroll
    for (int r = 0; r < 8; r++)
        #pragma unroll
        for (int c = 0; c < 8; c++) acc[r][c] = 0.f;

    // prefetch chunk 0
    float4 av[4], bv[4];
    #pragma unroll
    for (int i = 0; i < 4; i++) {
        int r = srow + i * 32;
        av[i] = *(const float4*)(s + (row0 + r) * HID + scol);
        bv[i] = *(const float4*)(wn + (size_t)r * HID + scol);
    }

    for (int ch = 0; ch < 8; ch++) {
        const bool first_half = (ch < 4);
        __syncthreads();  // LDS free (also covers invc_s for ch==0)
        // write staged tile (A scaled by invc for the s-half)
        #pragma unroll
        for (int i = 0; i < 4; i++) {
            int r = srow + i * 32;
            float ic = first_half ? invc_s[r] : 1.f;
            As[(scol + 0) * GP + r] = av[i].x * ic;
            As[(scol + 1) * GP + r] = av[i].y * ic;
            As[(scol + 2) * GP + r] = av[i].z * ic;
            As[(scol + 3) * GP + r] = av[i].w * ic;
            Bs[(scol + 0) * GP + r] = bv[i].x;
            Bs[(scol + 1) * GP + r] = bv[i].y;
            Bs[(scol + 2) * GP + r] = bv[i].z;
            Bs[(scol + 3) * GP + r] = bv[i].w;
        }
        __syncthreads();
        // prefetch next chunk (overlaps compute)
        if (ch + 1 < 8) {
            const float* xsrc = (ch + 1 < 4) ? s : xin;
            const float* wsrc = (ch + 1 < 4) ? wn : wr;
            int kofs = ((ch + 1) & 3) * 32;
            #pragma unroll
            for (int i = 0; i < 4; i++) {
                int r = srow + i * 32;
                av[i] = *(const float4*)(xsrc + (row0 + r) * HID + kofs + scol);
                bv[i] = *(const float4*)(wsrc + (size_t)r * HID + kofs + scol);
            }
        }
        // compute 32 k-steps
        #pragma unroll 2
        for (int k = 0; k < 32; k++) {
            float4 a0 = *(const float4*)&As[k * GP + tr * 8];
            float4 a1 = *(const float4*)&As[k * GP + tr * 8 + 4];
            float4 b0 = *(const float4*)&Bs[k * GP + tc * 4];
            float4 b1 = *(const float4*)&Bs[k * GP + 64 + tc * 4];
            float a[8] = {a0.x, a0.y, a0.z, a0.w, a1.x, a1.y, a1.z, a1.w};
            float bb8[8] = {b0.x, b0.y, b0.z, b0.w, b1.x, b1.y, b1.z, b1.w};
            #pragma unroll
            for (int r = 0; r < 8; r++)
                #pragma unroll
                for (int c = 0; c < 8; c++) acc[r][c] += a[r] * bb8[c];
        }
    }

    // epilogue: bias + relu, coalesced float4 stores
    float4 bias0 = *(const float4*)&bb[tc * 4];
    float4 bias1 = *(const float4*)&bb[64 + tc * 4];
    #pragma unroll
    for (int r = 0; r < 8; r++) {
        long m = row0 + tr * 8 + r;
        float4 o0, o1;
        o0.x = fmaxf(acc[r][0] + bias0.x, 0.f);
        o0.y = fmaxf(acc[r][1] + bias0.y, 0.f);
        o0.z = fmaxf(acc[r][2] + bias0.z, 0.f);
        o0.w = fmaxf(acc[r][3] + bias0.w, 0.f);
        o1.x = fmaxf(acc[r][4] + bias1.x, 0.f);
        o1.y = fmaxf(acc[r][5] + bias1.y, 0.f);
        o1.z = fmaxf(acc[r][6] + bias1.z, 0.f);
        o1.w = fmaxf(acc[r][7] + bias1.w, 0.f);
        *(float4*)(out + m * HID + tc * 4) = o0;
        *(float4*)(out + m * HID + 64 + tc * 4) = o1;
    }
}

// ---------------------------------------------------------------------------
// TopK pool: score = tanh(x.p/||p||); select top-k per graph with
// jax.lax.top_k semantics (descending, lower index wins ties); write
// xout[g*k+rank] = x[node]*score and mapping (old global id -> new or -1).
__global__ __launch_bounds__(256) void k_pool(const float* __restrict__ x,
                       const float* __restrict__ p,
                       int npc, int k,
                       float* __restrict__ xout,
                       int* __restrict__ mapping) {
    int g = blockIdx.x;
    int tid = threadIdx.x;  // 256
    __shared__ float sc[256];
    __shared__ int   pos[256];
    __shared__ float red[256];
    // ||p||
    float v = 0.f;
    if (tid < HID) { float t = p[tid]; v = t * t; }
    red[tid] = v;
    __syncthreads();
    for (int off = 128; off >= 1; off >>= 1) {
        if (tid < off) red[tid] += red[tid + off];
        __syncthreads();
    }
    float nrm = sqrtf(red[0]);
    // scores
    float scv = 0.f;
    if (tid < npc) {
        const float* xr = x + (long)(g * npc + tid) * HID;
        float d = 0.f;
        #pragma unroll 4
        for (int j = 0; j < HID; j++) d += xr[j] * p[j];
        scv = tanhf(d / nrm);
        sc[tid] = scv;
    }
    __syncthreads();
    // rank = position in descending stable order
    if (tid < npc) {
        int rank = 0;
        for (int j = 0; j < npc; j++) {
            float o = sc[j];
            rank += (o > scv) || (o == scv && j < tid);
        }
        bool keep = rank < k;
        pos[tid] = keep ? rank : -1;
        mapping[g * npc + tid] = keep ? (g * k + rank) : -1;
    }
    __syncthreads();
    // gather + scale into new ordering
    for (int idx = tid; idx < npc * HID; idx += 256) {
        int i = idx >> 7, h = idx & 127;
        int r = pos[i];
        if (r >= 0)
            xout[(long)(g * k + r) * HID + h] = x[(long)(g * npc + i) * HID + h] * sc[i];
    }
}

// ---------------------------------------------------------------------------
// Edge remap after pooling. May run in-place (sin==sout etc): each thread
// reads then writes only its own slot.
__global__ __launch_bounds__(256) void k_edgeupd(const int* sin, const int* din, const int* vin,
                          const int* __restrict__ mapping,
                          int* sout, int* dout, int* vout) {
    int e = blockIdx.x * blockDim.x + threadIdx.x;
    if (e < E) {
        int v  = vin ? vin[e] : 1;
        int ns = mapping[sin[e]];
        int nd = mapping[din[e]];
        int nv = (v && ns >= 0 && nd >= 0) ? 1 : 0;
        sout[e] = ns >= 0 ? ns : 0;
        dout[e] = nd >= 0 ? nd : 0;
        vout[e] = nv;
    }
}

// ---------------------------------------------------------------------------
// Global pool: gout[g][0:128]=max over k rows, gout[g][128:256]=mean.
__global__ __launch_bounds__(128) void k_gpool(const float* __restrict__ x, int k,
                        float* __restrict__ gout) {
    int g = blockIdx.x, h = threadIdx.x;  // 128 threads
    float mx = -INFINITY, sm = 0.f;
    for (int i = 0; i < k; i++) {
        float v = x[(long)(g * k + i) * HID + h];
        mx = fmaxf(mx, v);
        sm += v;
    }
    gout[g * 256 + h] = mx;
    gout[g * 256 + 128 + h] = sm / (float)k;
}

// ---------------------------------------------------------------------------
// MLP head: h=g1+g2+g3; relu(h@lw1.T+lb1); relu(@lw2.T+lb2); sigmoid(@lw3.T+lb3)
__global__ __launch_bounds__(128) void k_mlp(const float* __restrict__ g1, const float* __restrict__ g2,
                      const float* __restrict__ g3,
                      const float* __restrict__ lw1, const float* __restrict__ lb1,
                      const float* __restrict__ lw2, const float* __restrict__ lb2,
                      const float* __restrict__ lw3, const float* __restrict__ lb3,
                      float* __restrict__ out) {
    int g = blockIdx.x, t = threadIdx.x;  // 128 threads
    __shared__ float h0[256];
    __shared__ float h1[128];
    __shared__ float h2r[64];
    h0[t]       = g1[g * 256 + t] + g2[g * 256 + t] + g3[g * 256 + t];
    h0[t + 128] = g1[g * 256 + 128 + t] + g2[g * 256 + 128 + t] + g3[g * 256 + 128 + t];
    __syncthreads();
    float a = lb1[t];
    #pragma unroll 4
    for (int j = 0; j < 256; j++) a += h0[j] * lw1[t * 256 + j];
    h1[t] = fmaxf(a, 0.f);
    __syncthreads();
    if (t < 64) {
        float a2 = lb2[t];
        #pragma unroll 4
        for (int j = 0; j < 128; j++) a2 += h1[j] * lw2[t * 128 + j];
        h2r[t] = fmaxf(a2, 0.f) * lw3[t];
    }
    __syncthreads();
    if (t == 0) {
        float s = 0.f;
        for (int j = 0; j < 64; j++) s += h2r[j];
        s += lb3[0];
        out[g] = 1.f / (1.f + expf(-s));
    }
}

// ---------------------------------------------------------------------------
extern "C" void kernel_launch(void* const* d_in, const int* in_sizes, int n_in,
                              void* d_out, int out_size, void* d_ws, size_t ws_size,
                              hipStream_t stream) {
    const int*   node_ids = (const int*)d_in[0];
    const int*   ei   = (const int*)d_in[1];   // edge_index (2, E)
    const float* emb  = (const float*)d_in[3];
    const float* w1n  = (const float*)d_in[4];
    const float* w1r  = (const float*)d_in[5];
    const float* b1   = (const float*)d_in[6];
    const float* w2n  = (const float*)d_in[7];
    const float* w2r  = (const float*)d_in[8];
    const float* b2   = (const float*)d_in[9];
    const float* w3n  = (const float*)d_in[10];
    const float* w3r  = (const float*)d_in[11];
    const float* b3   = (const float*)d_in[12];
    const float* p1   = (const float*)d_in[13];
    const float* p2   = (const float*)d_in[14];
    const float* p3   = (const float*)d_in[15];
    const float* lw1  = (const float*)d_in[16];
    const float* lb1  = (const float*)d_in[17];
    const float* lw2  = (const float*)d_in[18];
    const float* lb2  = (const float*)d_in[19];
    const float* lw3  = (const float*)d_in[20];
    const float* lb3  = (const float*)d_in[21];
    float* out = (float*)d_out;

    // Workspace layout (floats). x0/s9 alias the front of D (dead before
    // D's first real use as pool-1 output).
    float* ws  = (float*)d_ws;
    float* C   = ws;                           // N0*HID   (x1 / s-acc / x2 / s3 / x3)
    float* D   = C + (size_t)N0 * HID;         // N1*HID   (x1p / x2p / x3p)
    float* x0  = D;                            // N0*EMB   (stage 1 only)
    float* s9  = D + (size_t)N0 * EMB;         // N0*EMB   (stage 1 only)
    float* cnt = D + (size_t)N1 * HID;         // N0
    float* g1  = cnt + N0;                     // B*256
    float* g2  = g1 + B * 2 * HID;             // B*256
    float* g3  = g2 + B * 2 * HID;             // B*256
    int* mapping = (int*)(g3 + B * 2 * HID);   // N0
    int* esrc  = mapping + N0;                 // E
    int* edst  = esrc + E;                     // E
    int* evalid = edst + E;                    // E

    // ---- Stage 1 (EMB -> HID) ----
    k_gather<<<(N0 + 255) / 256, 256, 0, stream>>>(node_ids, emb, x0);
    k_agg9<<<B, 256, 0, stream>>>(x0, ei, ei + E, s9, cnt);
    k_conv1<8><<<N0 / 8, 128, 0, stream>>>(s9, cnt, x0, w1n, w1r, b1, C);
    k_pool<<<B, 256, 0, stream>>>(C, p1, NPG, K1, D, mapping);
    k_edgeupd<<<(E + 255) / 256, 256, 0, stream>>>(ei, ei + E, nullptr, mapping,
                                                   esrc, edst, evalid);
    k_gpool<<<B, 128, 0, stream>>>(D, K1, g1);

    // ---- Stage 2 (HID -> HID), nodes N1 ----
    k_aggcsr<<<dim3(B, 2), 256, 0, stream>>>(D, esrc, edst, evalid, K1, C, cnt);
    k_convgemm<<<N1 / 128, 256, 0, stream>>>(C, cnt, D, w2n, w2r, b2, C);
    k_pool<<<B, 256, 0, stream>>>(C, p2, K1, K2, D, mapping);
    k_edgeupd<<<(E + 255) / 256, 256, 0, stream>>>(esrc, edst, evalid, mapping,
                                                   esrc, edst, evalid);
    k_gpool<<<B, 128, 0, stream>>>(D, K2, g2);

    // ---- Stage 3 (HID -> HID), nodes N2 ----
    k_aggcsr<<<dim3(B, 2), 256, 0, stream>>>(D, esrc, edst, evalid, K2, C, cnt);
    k_convgemm<<<N2 / 128, 256, 0, stream>>>(C, cnt, D, w3n, w3r, b3, C);
    k_pool<<<B, 256, 0, stream>>>(C, p3, K2, K3, D, mapping);
    // (final edge update is unused by the reference output -> skipped)
    k_gpool<<<B, 128, 0, stream>>>(D, K3, g3);

    // ---- Head ----
    k_mlp<<<B, 128, 0, stream>>>(g1, g2, g3, lw1, lb1, lw2, lb2, lw3, lb3, out);
}